// Round 1
// 1572.411 us; speedup vs baseline: 1.6016x; 1.6016x over previous
//
#include <hip/hip_runtime.h>
#include <stdint.h>
#include <stddef.h>

typedef __bf16 bf16_t;
typedef __bf16 bf16x8 __attribute__((ext_vector_type(8)));
typedef _Float16 halfx2 __attribute__((ext_vector_type(2)));
typedef float floatx4 __attribute__((ext_vector_type(4)));

#define N_ROWS 16384
#define DIM    1024

__device__ inline bf16x8 cvt_f32x8_bf16(const float* __restrict__ p) {
    floatx4 a = *(const floatx4*)p;
    floatx4 b = *(const floatx4*)(p + 4);
    bf16x8 r;
    r[0] = (bf16_t)a[0]; r[1] = (bf16_t)a[1]; r[2] = (bf16_t)a[2]; r[3] = (bf16_t)a[3];
    r[4] = (bf16_t)b[0]; r[5] = (bf16_t)b[1]; r[6] = (bf16_t)b[2]; r[7] = (bf16_t)b[3];
    return r;
}

__device__ inline void gload_lds16(const bf16_t* g, bf16_t* l) {
    // async global->LDS, 16B per lane; LDS dest = wave-uniform base + lane*16
    __builtin_amdgcn_global_load_lds(
        (const __attribute__((address_space(1))) void*)g,
        (__attribute__((address_space(3))) void*)l,
        16, 0, 0);
}

// ---------------- f32 -> bf16 batched converter ----------------
struct CvtBatch { const float* src[10]; };

__global__ __launch_bounds__(256) void cvt_f32_bf16_kernel(CvtBatch cb, bf16_t* __restrict__ dst, size_t per) {
    const size_t i = ((size_t)blockIdx.x * 256 + threadIdx.x) * 8;
    const float* s = cb.src[blockIdx.z] + i;
    bf16_t* d = dst + (size_t)blockIdx.z * per + i;
    *(bf16x8*)d = cvt_f32x8_bf16(s);
}

// ---------------- bf16 B^T GEMM, m97 structure ----------------
// C[m,n] = sum_k A[m,k]*B[n,k] + bias[n]. 128x128 tile, BK=32, 256 thr (2x2 waves).
// A,B bf16 K-contiguous. blockIdx.z selects the batched problem.
struct GemmBatch {
    const bf16_t* A[9];
    const bf16_t* B[9];
    const float*  bias[9];
    void*         C[9];
};

template<bool CF32, bool RELU>
__global__ __launch_bounds__(256) void gemm_bt16(GemmBatch g) {
    const int K = 1024, NN = 1024;
    const int bm = blockIdx.y, bn = blockIdx.x, z = blockIdx.z;
    const int t = threadIdx.x, lane = t & 63;
    const int w = t >> 6, wm = w & 1, wn = w >> 1;

    __shared__ __align__(16) bf16_t sA[128 * 32];
    __shared__ __align__(16) bf16_t sB[128 * 32];

    const bf16_t* __restrict__ A = g.A[z];
    const bf16_t* __restrict__ B = g.B[z];

    floatx4 acc[4][4] = {};

    // staging: thread t -> 16B at LDS byte t*16 == row (t>>2), elem col (t&3)*8
    const int r  = t >> 2;
    const int ce = (t & 3) * 8;
    const bf16_t* gA = A + (size_t)(bm * 128 + r) * K + ce;
    const bf16_t* gB = B + (size_t)(bn * 128 + r) * K + ce;
    bf16_t* lA = &sA[(w * 64) * 8];   // wave-uniform base (hw adds lane*16B)
    bf16_t* lB = &sB[(w * 64) * 8];

    // MFMA A/B fragment: row = lane&15, k = (lane>>4)*8 .. +8  [m92/m97 verified]
    const int aoff = (lane & 15) * 32 + (lane >> 4) * 8;

    for (int kt = 0; kt < K / 32; ++kt) {
        __syncthreads();                 // all readers of previous tile done
        gload_lds16(gA,          lA);
        gload_lds16(gA + 64 * K, lA + 2048);
        gload_lds16(gB,          lB);
        gload_lds16(gB + 64 * K, lB + 2048);
        gA += 32; gB += 32;
        __syncthreads();                 // vmcnt(0) drain before barrier: tile landed

        bf16x8 af[4], bfr[4];
#pragma unroll
        for (int i = 0; i < 4; ++i)
            af[i] = *(const bf16x8*)&sA[(wm * 64 + i * 16) * 32 + aoff];
#pragma unroll
        for (int j = 0; j < 4; ++j)
            bfr[j] = *(const bf16x8*)&sB[(wn * 64 + j * 16) * 32 + aoff];
#pragma unroll
        for (int i = 0; i < 4; ++i)
#pragma unroll
            for (int j = 0; j < 4; ++j)
                acc[i][j] = __builtin_amdgcn_mfma_f32_16x16x32_bf16(af[i], bfr[j], acc[i][j], 0, 0, 0);
    }

    // epilogue: C/D layout col=lane&15, row=(lane>>4)*4 + rr  [verified m89]
    const int col = lane & 15;
    const int rbase = (lane >> 4) * 4;
    const float* bias = g.bias[z];
#pragma unroll
    for (int j = 0; j < 4; ++j) {
        const int gn = bn * 128 + wn * 64 + j * 16 + col;
        const float bj = bias[gn];
#pragma unroll
        for (int i = 0; i < 4; ++i) {
            const int gm0 = bm * 128 + wm * 64 + i * 16 + rbase;
#pragma unroll
            for (int rr = 0; rr < 4; ++rr) {
                float v = acc[i][j][rr] + bj;
                if (RELU) v = v > 0.f ? v : 0.f;
                const size_t idx = (size_t)(gm0 + rr) * NN + gn;
                if constexpr (CF32) ((float*)g.C[z])[idx] = v;
                else                ((bf16_t*)g.C[z])[idx] = (bf16_t)v;
            }
        }
    }
}

// ---------------- barrier-free wave-per-row attention ----------------
// Block = 256 thr = 4 independent waves; wave w handles row n = bid*4+w, all 3 attns.
// Lane = e during QK (softmax over d is register-local), lane = d during PV.
// All LDS is wave-private -> NO __syncthreads anywhere (per-wave DS is in-order).
__device__ __forceinline__ void attn_one(const bf16_t* __restrict__ qp,
                                         const bf16_t* __restrict__ kp,
                                         const bf16_t* __restrict__ vp,
                                         bf16_t* __restrict__ sQw,
                                         bf16_t* __restrict__ sVw,
                                         _Float16* __restrict__ sWw,
                                         int lane, float o[16]) {
    // coalesced global loads: Q,V rows (2KB each) via 2x16B per lane; K via 16x2B
    bf16x8 q0 = *(const bf16x8*)(qp + lane * 8);
    bf16x8 q1 = *(const bf16x8*)(qp + 512 + lane * 8);
    bf16x8 v0 = *(const bf16x8*)(vp + lane * 8);
    bf16x8 v1 = *(const bf16x8*)(vp + 512 + lane * 8);
    bf16_t kr[16];
#pragma unroll
    for (int h = 0; h < 16; ++h) kr[h] = kp[h * 64 + lane];  // K[e,h], e=lane

    *(bf16x8*)(sQw + lane * 8)       = q0;
    *(bf16x8*)(sQw + 512 + lane * 8) = q1;
    *(bf16x8*)(sVw + lane * 8)       = v0;
    *(bf16x8*)(sVw + 512 + lane * 8) = v1;

    float kreg[16];
#pragma unroll
    for (int h = 0; h < 16; ++h) kreg[h] = (float)kr[h];

    // s[d] = sum_h Q[d,h]*K[e,h]; Q[d,h] = row_q[h*64+d] via LDS broadcast reads
    float s[64];
#pragma unroll
    for (int d = 0; d < 64; ++d) s[d] = 0.f;
#pragma unroll
    for (int h = 0; h < 16; ++h) {
#pragma unroll
        for (int j = 0; j < 8; ++j) {
            bf16x8 q8 = *(const bf16x8*)(sQw + h * 64 + j * 8);
#pragma unroll
            for (int u = 0; u < 8; ++u)
                s[j * 8 + u] += (float)q8[u] * kreg[h];
        }
    }

    float m = -1e30f;
#pragma unroll
    for (int d = 0; d < 64; ++d) { s[d] *= 0.125f; m = fmaxf(m, s[d]); }
    float sum = 0.f;
#pragma unroll
    for (int d = 0; d < 64; ++d) { s[d] = __expf(s[d] - m); sum += s[d]; }
    const float inv = __builtin_amdgcn_rcpf(sum);
#pragma unroll
    for (int d = 0; d < 64; ++d) sWw[d * 66 + lane] = (_Float16)(s[d] * inv);

    // transpose read: lane = d now; row stride 66 f16 (132B) -> conflict-free
    float wreg[64];
    {
        const halfx2* wrow = (const halfx2*)(sWw + lane * 66);
#pragma unroll
        for (int e2 = 0; e2 < 32; ++e2) {
            halfx2 hv = wrow[e2];
            wreg[2 * e2]     = (float)hv[0];
            wreg[2 * e2 + 1] = (float)hv[1];
        }
    }

    // o[d,h] += sum_e w[d,e]*V[e,h]; V[e,h] = row_v[h*64+e] via LDS broadcast
#pragma unroll
    for (int h = 0; h < 16; ++h) {
#pragma unroll
        for (int j = 0; j < 8; ++j) {
            bf16x8 v8 = *(const bf16x8*)(sVw + h * 64 + j * 8);
#pragma unroll
            for (int u = 0; u < 8; ++u)
                o[h] += (float)v8[u] * wreg[j * 8 + u];
        }
    }
}

__global__ __launch_bounds__(256) void attn_kernel(const bf16_t* __restrict__ proj,
                                                   size_t sstride,
                                                   bf16_t* __restrict__ avg) {
    __shared__ __align__(16) bf16_t sQ[4][1024];     // 8 KB
    __shared__ __align__(16) bf16_t sV[4][1024];     // 8 KB
    __shared__ _Float16 sW[4][64 * 66];              // 33 KB  -> 50176 B total, 3 blk/CU
    const int t = threadIdx.x, w = t >> 6, lane = t & 63;
    const int n = blockIdx.x * 4 + w;
    const bf16_t* base = proj + (size_t)n * DIM;

    float o[16];
#pragma unroll
    for (int h = 0; h < 16; ++h) o[h] = 0.f;

#pragma unroll
    for (int a = 0; a < 3; ++a)
        attn_one(base + (size_t)(3 * a)     * sstride,
                 base + (size_t)(3 * a + 1) * sstride,
                 base + (size_t)(3 * a + 2) * sstride,
                 sQ[w], sV[w], sW[w], lane, o);

    // out[n, h*64+d] = mean_a o_a[d,h]; lane=d -> coalesced 128B stores
    const float inv3 = 1.f / 3.f;
    bf16_t* out = avg + (size_t)n * DIM;
#pragma unroll
    for (int h = 0; h < 16; ++h) out[h * 64 + lane] = (bf16_t)(o[h] * inv3);
}

extern "C" void kernel_launch(void* const* d_in, const int* in_sizes, int n_in,
                              void* d_out, int out_size, void* d_ws, size_t ws_size,
                              hipStream_t stream) {
    const float* query = (const float*)d_in[0];
    const float* key_  = (const float*)d_in[1];
    const float* value = (const float*)d_in[2];
    const float* Wq1 = (const float*)d_in[3];  const float* bq1 = (const float*)d_in[4];
    const float* Wk1 = (const float*)d_in[5];  const float* bk1 = (const float*)d_in[6];
    const float* Wv1 = (const float*)d_in[7];  const float* bv1 = (const float*)d_in[8];
    const float* Wq2 = (const float*)d_in[9];  const float* bq2 = (const float*)d_in[10];
    const float* Wk2 = (const float*)d_in[11]; const float* bk2 = (const float*)d_in[12];
    const float* Wv2 = (const float*)d_in[13]; const float* bv2 = (const float*)d_in[14];
    const float* Wq3 = (const float*)d_in[15]; const float* bq3 = (const float*)d_in[16];
    const float* Wk3 = (const float*)d_in[17]; const float* bk3 = (const float*)d_in[18];
    const float* Wv3 = (const float*)d_in[19]; const float* bv3 = (const float*)d_in[20];
    const float* Wo  = (const float*)d_in[21]; const float* bo  = (const float*)d_in[22];

    // ws layout:
    //   wB   : 10 x 1024x1024 bf16 weights (proj slot order + Wo)     20.97 MB
    //   inB  : 3 x N x 1024 bf16 inputs (query, key, value)          100.66 MB
    //   proj : 9 x CH x 1024 bf16
    //   avgb : CH x 1024 bf16
    bf16_t* wB   = (bf16_t*)d_ws;
    bf16_t* inB  = wB + (size_t)10 * 1024 * 1024;
    bf16_t* proj = inB + (size_t)3 * N_ROWS * DIM;

    const size_t fixed = ((size_t)10 * 1024 * 1024 + (size_t)3 * N_ROWS * DIM) * sizeof(bf16_t);
    size_t rem = ws_size > fixed ? ws_size - fixed : 0;
    size_t ch = rem / (10 * DIM * sizeof(bf16_t));
    if (ch > N_ROWS) ch = N_ROWS;
    int CH = (int)((ch / 128) * 128);
    if (CH < 128) CH = 128;
    bf16_t* avgb = proj + (size_t)9 * CH * DIM;
    const size_t sstride = (size_t)CH * DIM;

    // one-time conversions to bf16
    CvtBatch cw;
    const float* worder[10] = {Wq1, Wk2, Wv1, Wq2, Wk1, Wv2, Wq3, Wk3, Wv3, Wo};
    for (int i = 0; i < 10; ++i) cw.src[i] = worder[i];
    cvt_f32_bf16_kernel<<<dim3(512, 1, 10), 256, 0, stream>>>(cw, wB, (size_t)1024 * 1024);

    CvtBatch ci;
    ci.src[0] = query; ci.src[1] = key_; ci.src[2] = value;
    for (int i = 3; i < 10; ++i) ci.src[i] = query;  // unused
    cvt_f32_bf16_kernel<<<dim3(8192, 1, 3), 256, 0, stream>>>(ci, inB, (size_t)N_ROWS * DIM);

    // slot i uses input ain[i] and weight wB+i (order matches worder / reference wiring)
    static const int ain[9] = {0, 2, 1, 2, 1, 0, 1, 0, 2};
    const float* bs[9] = {bq1, bk2, bv1, bq2, bk1, bv2, bq3, bk3, bv3};

    for (int r0 = 0; r0 < N_ROWS; r0 += CH) {
        const int rows = (N_ROWS - r0 < CH) ? (N_ROWS - r0) : CH;  // multiple of 128

        GemmBatch gp;
        for (int i = 0; i < 9; ++i) {
            gp.A[i]    = inB + ((size_t)ain[i] * N_ROWS + r0) * DIM;
            gp.B[i]    = wB + (size_t)i * 1024 * 1024;
            gp.bias[i] = bs[i];
            gp.C[i]    = proj + (size_t)i * sstride;
        }
        gemm_bt16<false, false><<<dim3(8, rows / 128, 9), 256, 0, stream>>>(gp);

        attn_kernel<<<dim3(rows / 4), 256, 0, stream>>>(proj, sstride, avgb);

        GemmBatch gf;
        gf.A[0] = avgb;
        gf.B[0] = wB + (size_t)9 * 1024 * 1024;
        gf.bias[0] = bo;
        gf.C[0] = (float*)d_out + (size_t)r0 * DIM;
        for (int i = 1; i < 9; ++i) { gf.A[i] = gf.A[0]; gf.B[i] = gf.B[0]; gf.bias[i] = gf.bias[0]; gf.C[i] = gf.C[0]; }
        gemm_bt16<true, true><<<dim3(8, rows / 128, 1), 256, 0, stream>>>(gf);
    }
}

// Round 2
// 970.667 us; speedup vs baseline: 2.5945x; 1.6199x over previous
//
#include <hip/hip_runtime.h>
#include <stdint.h>
#include <stddef.h>

typedef __bf16 bf16_t;
typedef __bf16 bf16x4 __attribute__((ext_vector_type(4)));
typedef __bf16 bf16x8 __attribute__((ext_vector_type(8)));
typedef float floatx4 __attribute__((ext_vector_type(4)));

#define N_ROWS 16384
#define DIM    1024

__device__ inline bf16x8 cvt_f32x8_bf16(const float* __restrict__ p) {
    floatx4 a = *(const floatx4*)p;
    floatx4 b = *(const floatx4*)(p + 4);
    bf16x8 r;
    r[0] = (bf16_t)a[0]; r[1] = (bf16_t)a[1]; r[2] = (bf16_t)a[2]; r[3] = (bf16_t)a[3];
    r[4] = (bf16_t)b[0]; r[5] = (bf16_t)b[1]; r[6] = (bf16_t)b[2]; r[7] = (bf16_t)b[3];
    return r;
}

__device__ inline void gload_lds16(const bf16_t* g, bf16_t* l) {
    __builtin_amdgcn_global_load_lds(
        (const __attribute__((address_space(1))) void*)g,
        (__attribute__((address_space(3))) void*)l,
        16, 0, 0);
}

// ---------------- f32 -> bf16 batched converter ----------------
struct CvtBatch { const float* src[10]; };

__global__ __launch_bounds__(256) void cvt_f32_bf16_kernel(CvtBatch cb, bf16_t* __restrict__ dst, size_t per) {
    const size_t i = ((size_t)blockIdx.x * 256 + threadIdx.x) * 8;
    const float* s = cb.src[blockIdx.z] + i;
    bf16_t* d = dst + (size_t)blockIdx.z * per + i;
    *(bf16x8*)d = cvt_f32x8_bf16(s);
}

// ---------------- bf16 B^T GEMM, m97 structure (unchanged) ----------------
struct GemmBatch {
    const bf16_t* A[9];
    const bf16_t* B[9];
    const float*  bias[9];
    void*         C[9];
};

template<bool CF32, bool RELU>
__global__ __launch_bounds__(256) void gemm_bt16(GemmBatch g) {
    const int K = 1024, NN = 1024;
    const int bm = blockIdx.y, bn = blockIdx.x, z = blockIdx.z;
    const int t = threadIdx.x, lane = t & 63;
    const int w = t >> 6, wm = w & 1, wn = w >> 1;

    __shared__ __align__(16) bf16_t sA[128 * 32];
    __shared__ __align__(16) bf16_t sB[128 * 32];

    const bf16_t* __restrict__ A = g.A[z];
    const bf16_t* __restrict__ B = g.B[z];

    floatx4 acc[4][4] = {};

    const int r  = t >> 2;
    const int ce = (t & 3) * 8;
    const bf16_t* gA = A + (size_t)(bm * 128 + r) * K + ce;
    const bf16_t* gB = B + (size_t)(bn * 128 + r) * K + ce;
    bf16_t* lA = &sA[(w * 64) * 8];
    bf16_t* lB = &sB[(w * 64) * 8];

    const int aoff = (lane & 15) * 32 + (lane >> 4) * 8;

    for (int kt = 0; kt < K / 32; ++kt) {
        __syncthreads();
        gload_lds16(gA,          lA);
        gload_lds16(gA + 64 * K, lA + 2048);
        gload_lds16(gB,          lB);
        gload_lds16(gB + 64 * K, lB + 2048);
        gA += 32; gB += 32;
        __syncthreads();

        bf16x8 af[4], bfr[4];
#pragma unroll
        for (int i = 0; i < 4; ++i)
            af[i] = *(const bf16x8*)&sA[(wm * 64 + i * 16) * 32 + aoff];
#pragma unroll
        for (int j = 0; j < 4; ++j)
            bfr[j] = *(const bf16x8*)&sB[(wn * 64 + j * 16) * 32 + aoff];
#pragma unroll
        for (int i = 0; i < 4; ++i)
#pragma unroll
            for (int j = 0; j < 4; ++j)
                acc[i][j] = __builtin_amdgcn_mfma_f32_16x16x32_bf16(af[i], bfr[j], acc[i][j], 0, 0, 0);
    }

    const int col = lane & 15;
    const int rbase = (lane >> 4) * 4;
    const float* bias = g.bias[z];
#pragma unroll
    for (int j = 0; j < 4; ++j) {
        const int gn = bn * 128 + wn * 64 + j * 16 + col;
        const float bj = bias[gn];
#pragma unroll
        for (int i = 0; i < 4; ++i) {
            const int gm0 = bm * 128 + wm * 64 + i * 16 + rbase;
#pragma unroll
            for (int rr = 0; rr < 4; ++rr) {
                float v = acc[i][j][rr] + bj;
                if (RELU) v = v > 0.f ? v : 0.f;
                const size_t idx = (size_t)(gm0 + rr) * NN + gn;
                if constexpr (CF32) ((float*)g.C[z])[idx] = v;
                else                ((bf16_t*)g.C[z])[idx] = (bf16_t)v;
            }
        }
    }
}

// ---------------- MFMA wave-per-row attention (barrier-free) ----------------
// Wave w handles row n = bid*4+w, all 3 attns accumulated in registers.
// QK^T: S[d,e] = sum_h Q[d,h]K[e,h], 16 x mfma_16x16x32 (k=h, zero-padded 16->32).
//   A-frag: m=d=16dt+(lane&15), k=(lane>>4)*8+u  [same pattern as verified GEMM]
//   C tile: col=e=16et+(lane&15), row-local d=(lane>>4)*4+r            [m89]
// softmax over d (axis=1): per column e, 16 in-lane values + shfl_xor(16,32)
//   over the 4-lane group {lane&15 + 16g}.
// PV: o[d,h] = sum_e w[d,e]V[e,h], 8 x mfma (A=w from LDS, B=V direct global).
// All LDS wave-private; per-wave DS is in-order -> NO __syncthreads.
__global__ __launch_bounds__(256) void attn_kernel(const bf16_t* __restrict__ proj,
                                                   size_t sstride,
                                                   bf16_t* __restrict__ avg) {
    // per wave: qT [64][40] elems at [0,2560), kT at [2560,5120),
    //           w  [64][72] elems at [0,4608) (reuses dead Q/K region)
    __shared__ __align__(16) bf16_t lds[4][5120];   // 40960 B
    const int t = threadIdx.x, w = t >> 6, lane = t & 63;
    const int n = blockIdx.x * 4 + w;
    const bf16_t* base = proj + (size_t)n * DIM;
    bf16_t* qT = lds[w];
    bf16_t* kT = lds[w] + 2560;
    bf16_t* wb = lds[w];

    const int q4 = lane & 15;   // column / m index within 16-tile
    const int h4 = lane >> 4;   // k-slice group 0..3

    floatx4 oacc[4] = {};       // o[d,h] accumulated over the 3 attentions

    for (int a = 0; a < 3; ++a) {
        const bf16_t* rq = base + (size_t)(3 * a)     * sstride;
        const bf16_t* rk = base + (size_t)(3 * a + 1) * sstride;
        const bf16_t* rv = base + (size_t)(3 * a + 2) * sstride;

        // zero k=16..31 halves (clobbered by w each iteration)
        bf16x8 z8 = {};
        *(bf16x8*)&qT[lane * 40 + 16] = z8;
        *(bf16x8*)&qT[lane * 40 + 24] = z8;
        *(bf16x8*)&kT[lane * 40 + 16] = z8;
        *(bf16x8*)&kT[lane * 40 + 24] = z8;

        // stage Q,K transposed: row elem (h*64+d) -> qT[d*40+h]
        {
            bf16x8 t0 = *(const bf16x8*)(rq + lane * 16);
            bf16x8 t1 = *(const bf16x8*)(rq + lane * 16 + 8);
            bf16x8 u0 = *(const bf16x8*)(rk + lane * 16);
            bf16x8 u1 = *(const bf16x8*)(rk + lane * 16 + 8);
            const int h  = lane >> 2;         // constant h per lane
            const int d0 = (lane & 3) * 16;   // 16 consecutive d
#pragma unroll
            for (int s2 = 0; s2 < 8; ++s2) {
                qT[(d0 + s2) * 40 + h]     = t0[s2];
                qT[(d0 + 8 + s2) * 40 + h] = t1[s2];
                kT[(d0 + s2) * 40 + h]     = u0[s2];
                kT[(d0 + 8 + s2) * 40 + h] = u1[s2];
            }
        }

        // fragment loads (b128, 16B-aligned; stride 40 avoids bank clustering)
        bf16x8 qf[4], kf[4];
#pragma unroll
        for (int i = 0; i < 4; ++i) {
            qf[i] = *(const bf16x8*)&qT[(16 * i + q4) * 40 + h4 * 8];
            kf[i] = *(const bf16x8*)&kT[(16 * i + q4) * 40 + h4 * 8];
        }

        floatx4 S[4][4];
#pragma unroll
        for (int dt = 0; dt < 4; ++dt)
#pragma unroll
            for (int et = 0; et < 4; ++et)
                S[dt][et] = __builtin_amdgcn_mfma_f32_16x16x32_bf16(
                    qf[dt], kf[et], (floatx4){0.f, 0.f, 0.f, 0.f}, 0, 0, 0);

        // softmax over d per column e, then w -> LDS [d][e] stride 72 (bf16)
#pragma unroll
        for (int et = 0; et < 4; ++et) {
            float mx = -1e30f;
#pragma unroll
            for (int dt = 0; dt < 4; ++dt)
#pragma unroll
                for (int rr = 0; rr < 4; ++rr) {
                    float v = S[dt][et][rr] * 0.125f;
                    S[dt][et][rr] = v;
                    mx = fmaxf(mx, v);
                }
            mx = fmaxf(mx, __shfl_xor(mx, 16));
            mx = fmaxf(mx, __shfl_xor(mx, 32));
            float sum = 0.f;
#pragma unroll
            for (int dt = 0; dt < 4; ++dt)
#pragma unroll
                for (int rr = 0; rr < 4; ++rr) {
                    float e = __expf(S[dt][et][rr] - mx);
                    S[dt][et][rr] = e;
                    sum += e;
                }
            sum += __shfl_xor(sum, 16);
            sum += __shfl_xor(sum, 32);
            const float inv = 1.f / sum;
#pragma unroll
            for (int dt = 0; dt < 4; ++dt)
#pragma unroll
                for (int rr = 0; rr < 4; ++rr)
                    wb[(16 * dt + h4 * 4 + rr) * 72 + 16 * et + q4] =
                        (bf16_t)(S[dt][et][rr] * inv);
        }

        // PV: A-frag w from LDS (m=d=16mt+q4, k=e=32ks+h4*8+u),
        //     B-frag V direct from global (n=h=q4, k=e slice, contiguous 16B)
#pragma unroll
        for (int ks = 0; ks < 2; ++ks) {
            bf16x8 vf = *(const bf16x8*)(rv + q4 * 64 + ks * 32 + h4 * 8);
#pragma unroll
            for (int mt = 0; mt < 4; ++mt) {
                bf16x8 wf = *(const bf16x8*)&wb[(16 * mt + q4) * 72 + ks * 32 + h4 * 8];
                oacc[mt] = __builtin_amdgcn_mfma_f32_16x16x32_bf16(wf, vf, oacc[mt], 0, 0, 0);
            }
        }
    }

    // store: out[h*64+d], h=q4, d=16mt+h4*4+r; packed 4-wide b64 stores
    bf16_t* out = avg + (size_t)n * DIM;
    const float inv3 = 1.f / 3.f;
#pragma unroll
    for (int mt = 0; mt < 4; ++mt) {
        bf16x4 pk;
#pragma unroll
        for (int rr = 0; rr < 4; ++rr) pk[rr] = (bf16_t)(oacc[mt][rr] * inv3);
        *(bf16x4*)(out + q4 * 64 + 16 * mt + h4 * 4) = pk;
    }
}

extern "C" void kernel_launch(void* const* d_in, const int* in_sizes, int n_in,
                              void* d_out, int out_size, void* d_ws, size_t ws_size,
                              hipStream_t stream) {
    const float* query = (const float*)d_in[0];
    const float* key_  = (const float*)d_in[1];
    const float* value = (const float*)d_in[2];
    const float* Wq1 = (const float*)d_in[3];  const float* bq1 = (const float*)d_in[4];
    const float* Wk1 = (const float*)d_in[5];  const float* bk1 = (const float*)d_in[6];
    const float* Wv1 = (const float*)d_in[7];  const float* bv1 = (const float*)d_in[8];
    const float* Wq2 = (const float*)d_in[9];  const float* bq2 = (const float*)d_in[10];
    const float* Wk2 = (const float*)d_in[11]; const float* bk2 = (const float*)d_in[12];
    const float* Wv2 = (const float*)d_in[13]; const float* bv2 = (const float*)d_in[14];
    const float* Wq3 = (const float*)d_in[15]; const float* bq3 = (const float*)d_in[16];
    const float* Wk3 = (const float*)d_in[17]; const float* bk3 = (const float*)d_in[18];
    const float* Wv3 = (const float*)d_in[19]; const float* bv3 = (const float*)d_in[20];
    const float* Wo  = (const float*)d_in[21]; const float* bo  = (const float*)d_in[22];

    bf16_t* wB   = (bf16_t*)d_ws;
    bf16_t* inB  = wB + (size_t)10 * 1024 * 1024;
    bf16_t* proj = inB + (size_t)3 * N_ROWS * DIM;

    const size_t fixed = ((size_t)10 * 1024 * 1024 + (size_t)3 * N_ROWS * DIM) * sizeof(bf16_t);
    size_t rem = ws_size > fixed ? ws_size - fixed : 0;
    size_t ch = rem / (10 * DIM * sizeof(bf16_t));
    if (ch > N_ROWS) ch = N_ROWS;
    int CH = (int)((ch / 128) * 128);
    if (CH < 128) CH = 128;
    bf16_t* avgb = proj + (size_t)9 * CH * DIM;
    const size_t sstride = (size_t)CH * DIM;

    CvtBatch cw;
    const float* worder[10] = {Wq1, Wk2, Wv1, Wq2, Wk1, Wv2, Wq3, Wk3, Wv3, Wo};
    for (int i = 0; i < 10; ++i) cw.src[i] = worder[i];
    cvt_f32_bf16_kernel<<<dim3(512, 1, 10), 256, 0, stream>>>(cw, wB, (size_t)1024 * 1024);

    CvtBatch ci;
    ci.src[0] = query; ci.src[1] = key_; ci.src[2] = value;
    for (int i = 3; i < 10; ++i) ci.src[i] = query;
    cvt_f32_bf16_kernel<<<dim3(8192, 1, 3), 256, 0, stream>>>(ci, inB, (size_t)N_ROWS * DIM);

    static const int ain[9] = {0, 2, 1, 2, 1, 0, 1, 0, 2};
    const float* bs[9] = {bq1, bk2, bv1, bq2, bk1, bv2, bq3, bk3, bv3};

    for (int r0 = 0; r0 < N_ROWS; r0 += CH) {
        const int rows = (N_ROWS - r0 < CH) ? (N_ROWS - r0) : CH;

        GemmBatch gp;
        for (int i = 0; i < 9; ++i) {
            gp.A[i]    = inB + ((size_t)ain[i] * N_ROWS + r0) * DIM;
            gp.B[i]    = wB + (size_t)i * 1024 * 1024;
            gp.bias[i] = bs[i];
            gp.C[i]    = proj + (size_t)i * sstride;
        }
        gemm_bt16<false, false><<<dim3(8, rows / 128, 9), 256, 0, stream>>>(gp);

        attn_kernel<<<dim3(rows / 4), 256, 0, stream>>>(proj, sstride, avgb);

        GemmBatch gf;
        gf.A[0] = avgb;
        gf.B[0] = wB + (size_t)9 * 1024 * 1024;
        gf.bias[0] = bo;
        gf.C[0] = (float*)d_out + (size_t)r0 * DIM;
        for (int i = 1; i < 9; ++i) { gf.A[i] = gf.A[0]; gf.B[i] = gf.B[0]; gf.bias[i] = gf.bias[0]; gf.C[i] = gf.C[0]; }
        gemm_bt16<true, true><<<dim3(8, rows / 128, 1), 256, 0, stream>>>(gf);
    }
}

// Round 3
// 921.404 us; speedup vs baseline: 2.7332x; 1.0535x over previous
//
#include <hip/hip_runtime.h>
#include <stdint.h>
#include <stddef.h>

typedef __bf16 bf16_t;
typedef __bf16 bf16x4 __attribute__((ext_vector_type(4)));
typedef __bf16 bf16x8 __attribute__((ext_vector_type(8)));
typedef float floatx4 __attribute__((ext_vector_type(4)));

#define N_ROWS 16384
#define DIM    1024

__device__ inline bf16x8 cvt_f32x8_bf16(const float* __restrict__ p) {
    floatx4 a = *(const floatx4*)p;
    floatx4 b = *(const floatx4*)(p + 4);
    bf16x8 r;
    r[0] = (bf16_t)a[0]; r[1] = (bf16_t)a[1]; r[2] = (bf16_t)a[2]; r[3] = (bf16_t)a[3];
    r[4] = (bf16_t)b[0]; r[5] = (bf16_t)b[1]; r[6] = (bf16_t)b[2]; r[7] = (bf16_t)b[3];
    return r;
}

__device__ inline void gload_lds16(const bf16_t* g, bf16_t* l) {
    __builtin_amdgcn_global_load_lds(
        (const __attribute__((address_space(1))) void*)g,
        (__attribute__((address_space(3))) void*)l,
        16, 0, 0);
}

// ---------------- f32 -> bf16 batched converter ----------------
struct CvtBatch { const float* src[10]; };

__global__ __launch_bounds__(256) void cvt_f32_bf16_kernel(CvtBatch cb, bf16_t* __restrict__ dst, size_t per) {
    const size_t i = ((size_t)blockIdx.x * 256 + threadIdx.x) * 8;
    const float* s = cb.src[blockIdx.z] + i;
    bf16_t* d = dst + (size_t)blockIdx.z * per + i;
    *(bf16x8*)d = cvt_f32x8_bf16(s);
}

// ---------------- bf16 B^T GEMM, m97 structure + XCD-L2 mapping ----------------
// C[m,n] = sum_k A[m,k]*B[n,k] + bias[n]. 128x128 tile, BK=32, 256 thr (2x2 waves).
// Flat grid; when nbm%8==0: XCD x (= flat&7, round-robin dispatch) owns the
// contiguous bm-stripe [x*nbm/8, (x+1)*nbm/8) (A-stripe ~1.8MB stays in its L2),
// and sweeps (bm_local fastest, then bn, then z) so A is re-read from L2 not HBM.
struct GemmBatch {
    const bf16_t* A[9];
    const bf16_t* B[9];
    const float*  bias[9];
    void*         C[9];
};

template<bool CF32, bool RELU>
__global__ __launch_bounds__(256) void gemm_bt16(GemmBatch g, int nbm, int nz) {
    const int K = 1024, NN = 1024;
    int bm, bn, z;
    {
        const int flat = blockIdx.x;
        if ((nbm & 7) == 0) {
            const int stripe = nbm >> 3;
            const int xcd = flat & 7;
            const int slot = flat >> 3;
            const int bml = slot % stripe;
            const int rest = slot / stripe;
            bn = rest & 7;
            z  = rest >> 3;
            bm = xcd * stripe + bml;
        } else {
            bn = flat & 7;
            const int r2 = flat >> 3;
            bm = r2 % nbm;
            z  = r2 / nbm;
        }
    }
    const int t = threadIdx.x, lane = t & 63;
    const int w = t >> 6, wm = w & 1, wn = w >> 1;

    __shared__ __align__(16) bf16_t sA[128 * 32];
    __shared__ __align__(16) bf16_t sB[128 * 32];

    const bf16_t* __restrict__ A = g.A[z];
    const bf16_t* __restrict__ B = g.B[z];

    floatx4 acc[4][4] = {};

    const int r  = t >> 2;
    const int ce = (t & 3) * 8;
    const bf16_t* gA = A + (size_t)(bm * 128 + r) * K + ce;
    const bf16_t* gB = B + (size_t)(bn * 128 + r) * K + ce;
    bf16_t* lA = &sA[(w * 64) * 8];
    bf16_t* lB = &sB[(w * 64) * 8];

    const int aoff = (lane & 15) * 32 + (lane >> 4) * 8;

    for (int kt = 0; kt < K / 32; ++kt) {
        __syncthreads();
        gload_lds16(gA,          lA);
        gload_lds16(gA + 64 * K, lA + 2048);
        gload_lds16(gB,          lB);
        gload_lds16(gB + 64 * K, lB + 2048);
        gA += 32; gB += 32;
        __syncthreads();

        bf16x8 af[4], bfr[4];
#pragma unroll
        for (int i = 0; i < 4; ++i)
            af[i] = *(const bf16x8*)&sA[(wm * 64 + i * 16) * 32 + aoff];
#pragma unroll
        for (int j = 0; j < 4; ++j)
            bfr[j] = *(const bf16x8*)&sB[(wn * 64 + j * 16) * 32 + aoff];
#pragma unroll
        for (int i = 0; i < 4; ++i)
#pragma unroll
            for (int j = 0; j < 4; ++j)
                acc[i][j] = __builtin_amdgcn_mfma_f32_16x16x32_bf16(af[i], bfr[j], acc[i][j], 0, 0, 0);
    }

    const int col = lane & 15;
    const int rbase = (lane >> 4) * 4;
    const float* bias = g.bias[z];
#pragma unroll
    for (int j = 0; j < 4; ++j) {
        const int gn = bn * 128 + wn * 64 + j * 16 + col;
        const float bj = bias[gn];
#pragma unroll
        for (int i = 0; i < 4; ++i) {
            const int gm0 = bm * 128 + wm * 64 + i * 16 + rbase;
#pragma unroll
            for (int rr = 0; rr < 4; ++rr) {
                float v = acc[i][j][rr] + bj;
                if (RELU) v = v > 0.f ? v : 0.f;
                const size_t idx = (size_t)(gm0 + rr) * NN + gn;
                if constexpr (CF32) ((float*)g.C[z])[idx] = v;
                else                ((bf16_t*)g.C[z])[idx] = (bf16_t)v;
            }
        }
    }
}

// ---------------- MFMA wave-per-row attention (barrier-free) ----------------
// Wave w handles row n = bid*4+w, all 3 attns accumulated in registers.
// Q/K MFMA frags built DIRECTLY from global (no LDS transpose):
//   lane(q4,h4) needs X[m=16i+q4, k=h=h4*8+u] = row[(h4*8+u)*64 + 16i+q4];
//   h>=16 is zero padding (K=32 mfma, 16 real h) -> lanes h4>=2 hold zeros.
// S C-tile: col=e=16et+q4, row-local d=(lane>>4)*4+rr  [m89]
// softmax over d: 16 in-lane + shfl_xor(16,32). w -> wave-private LDS [d][e]
// stride 72, then PV: A=w from LDS, B=V direct global. NO __syncthreads.
__global__ __launch_bounds__(256) void attn_kernel(const bf16_t* __restrict__ proj,
                                                   size_t sstride,
                                                   bf16_t* __restrict__ avg) {
    __shared__ __align__(16) bf16_t wlds[4][64 * 72];   // 36864 B
    const int t = threadIdx.x, w = t >> 6, lane = t & 63;
    const int n = blockIdx.x * 4 + w;
    const bf16_t* base = proj + (size_t)n * DIM;
    bf16_t* wb = wlds[w];

    const int q4 = lane & 15;   // m/n index within 16-tile
    const int h4 = lane >> 4;   // k-slice group 0..3

    floatx4 oacc[4] = {};       // o[d,h] accumulated over the 3 attentions

    for (int a = 0; a < 3; ++a) {
        const bf16_t* rq = base + (size_t)(3 * a)     * sstride;
        const bf16_t* rk = base + (size_t)(3 * a + 1) * sstride;
        const bf16_t* rv = base + (size_t)(3 * a + 2) * sstride;

        bf16x8 qf[4] = {}, kf[4] = {};
        if (h4 < 2) {
            const bf16_t* qb = rq + h4 * 8 * 64 + q4;   // u adds 64, i adds 16
            const bf16_t* kb = rk + h4 * 8 * 64 + q4;
#pragma unroll
            for (int i = 0; i < 4; ++i)
#pragma unroll
                for (int u = 0; u < 8; ++u) {
                    qf[i][u] = qb[u * 64 + i * 16];
                    kf[i][u] = kb[u * 64 + i * 16];
                }
        }

        floatx4 S[4][4];
#pragma unroll
        for (int dt = 0; dt < 4; ++dt)
#pragma unroll
            for (int et = 0; et < 4; ++et)
                S[dt][et] = __builtin_amdgcn_mfma_f32_16x16x32_bf16(
                    qf[dt], kf[et], (floatx4){0.f, 0.f, 0.f, 0.f}, 0, 0, 0);

        // softmax over d per column e, then w -> LDS [d][e] stride 72 (bf16)
#pragma unroll
        for (int et = 0; et < 4; ++et) {
            float mx = -1e30f;
#pragma unroll
            for (int dt = 0; dt < 4; ++dt)
#pragma unroll
                for (int rr = 0; rr < 4; ++rr) {
                    float v = S[dt][et][rr] * 0.125f;
                    S[dt][et][rr] = v;
                    mx = fmaxf(mx, v);
                }
            mx = fmaxf(mx, __shfl_xor(mx, 16));
            mx = fmaxf(mx, __shfl_xor(mx, 32));
            float sum = 0.f;
#pragma unroll
            for (int dt = 0; dt < 4; ++dt)
#pragma unroll
                for (int rr = 0; rr < 4; ++rr) {
                    float e = __expf(S[dt][et][rr] - mx);
                    S[dt][et][rr] = e;
                    sum += e;
                }
            sum += __shfl_xor(sum, 16);
            sum += __shfl_xor(sum, 32);
            const float inv = 1.f / sum;
#pragma unroll
            for (int dt = 0; dt < 4; ++dt)
#pragma unroll
                for (int rr = 0; rr < 4; ++rr)
                    wb[(16 * dt + h4 * 4 + rr) * 72 + 16 * et + q4] =
                        (bf16_t)(S[dt][et][rr] * inv);
        }

        // PV: A-frag w from LDS (m=d=16mt+q4, k=e=32ks+h4*8+u),
        //     B-frag V direct from global (n=h=q4, k=e slice, contiguous 16B)
#pragma unroll
        for (int ks = 0; ks < 2; ++ks) {
            bf16x8 vf = *(const bf16x8*)(rv + q4 * 64 + ks * 32 + h4 * 8);
#pragma unroll
            for (int mt = 0; mt < 4; ++mt) {
                bf16x8 wf = *(const bf16x8*)&wb[(16 * mt + q4) * 72 + ks * 32 + h4 * 8];
                oacc[mt] = __builtin_amdgcn_mfma_f32_16x16x32_bf16(wf, vf, oacc[mt], 0, 0, 0);
            }
        }
    }

    // store: out[h*64+d], h=q4, d=16mt+h4*4+rr; packed 4-wide b64 stores
    bf16_t* out = avg + (size_t)n * DIM;
    const float inv3 = 1.f / 3.f;
#pragma unroll
    for (int mt = 0; mt < 4; ++mt) {
        bf16x4 pk;
#pragma unroll
        for (int rr = 0; rr < 4; ++rr) pk[rr] = (bf16_t)(oacc[mt][rr] * inv3);
        *(bf16x4*)(out + q4 * 64 + 16 * mt + h4 * 4) = pk;
    }
}

extern "C" void kernel_launch(void* const* d_in, const int* in_sizes, int n_in,
                              void* d_out, int out_size, void* d_ws, size_t ws_size,
                              hipStream_t stream) {
    const float* query = (const float*)d_in[0];
    const float* key_  = (const float*)d_in[1];
    const float* value = (const float*)d_in[2];
    const float* Wq1 = (const float*)d_in[3];  const float* bq1 = (const float*)d_in[4];
    const float* Wk1 = (const float*)d_in[5];  const float* bk1 = (const float*)d_in[6];
    const float* Wv1 = (const float*)d_in[7];  const float* bv1 = (const float*)d_in[8];
    const float* Wq2 = (const float*)d_in[9];  const float* bq2 = (const float*)d_in[10];
    const float* Wk2 = (const float*)d_in[11]; const float* bk2 = (const float*)d_in[12];
    const float* Wv2 = (const float*)d_in[13]; const float* bv2 = (const float*)d_in[14];
    const float* Wq3 = (const float*)d_in[15]; const float* bq3 = (const float*)d_in[16];
    const float* Wk3 = (const float*)d_in[17]; const float* bk3 = (const float*)d_in[18];
    const float* Wv3 = (const float*)d_in[19]; const float* bv3 = (const float*)d_in[20];
    const float* Wo  = (const float*)d_in[21]; const float* bo  = (const float*)d_in[22];

    bf16_t* wB   = (bf16_t*)d_ws;
    bf16_t* inB  = wB + (size_t)10 * 1024 * 1024;
    bf16_t* proj = inB + (size_t)3 * N_ROWS * DIM;

    const size_t fixed = ((size_t)10 * 1024 * 1024 + (size_t)3 * N_ROWS * DIM) * sizeof(bf16_t);
    size_t rem = ws_size > fixed ? ws_size - fixed : 0;
    size_t ch = rem / (10 * DIM * sizeof(bf16_t));
    if (ch > N_ROWS) ch = N_ROWS;
    // prefer CH multiple of 1024 so nbm%8==0 enables the XCD-L2 mapping
    int CH = (int)((ch / 1024) * 1024);
    if (CH < 1024) {
        CH = (int)((ch / 128) * 128);
        if (CH < 128) CH = 128;
    }
    bf16_t* avgb = proj + (size_t)9 * CH * DIM;
    const size_t sstride = (size_t)CH * DIM;

    CvtBatch cw;
    const float* worder[10] = {Wq1, Wk2, Wv1, Wq2, Wk1, Wv2, Wq3, Wk3, Wv3, Wo};
    for (int i = 0; i < 10; ++i) cw.src[i] = worder[i];
    cvt_f32_bf16_kernel<<<dim3(512, 1, 10), 256, 0, stream>>>(cw, wB, (size_t)1024 * 1024);

    CvtBatch ci;
    ci.src[0] = query; ci.src[1] = key_; ci.src[2] = value;
    for (int i = 3; i < 10; ++i) ci.src[i] = query;
    cvt_f32_bf16_kernel<<<dim3(8192, 1, 3), 256, 0, stream>>>(ci, inB, (size_t)N_ROWS * DIM);

    static const int ain[9] = {0, 2, 1, 2, 1, 0, 1, 0, 2};
    const float* bs[9] = {bq1, bk2, bv1, bq2, bk1, bv2, bq3, bk3, bv3};

    for (int r0 = 0; r0 < N_ROWS; r0 += CH) {
        const int rows = (N_ROWS - r0 < CH) ? (N_ROWS - r0) : CH;
        const int nbm = rows / 128;

        GemmBatch gp;
        for (int i = 0; i < 9; ++i) {
            gp.A[i]    = inB + ((size_t)ain[i] * N_ROWS + r0) * DIM;
            gp.B[i]    = wB + (size_t)i * 1024 * 1024;
            gp.bias[i] = bs[i];
            gp.C[i]    = proj + (size_t)i * sstride;
        }
        gemm_bt16<false, false><<<dim3(nbm * 8 * 9), 256, 0, stream>>>(gp, nbm, 9);

        attn_kernel<<<dim3(rows / 4), 256, 0, stream>>>(proj, sstride, avgb);

        GemmBatch gf;
        gf.A[0] = avgb;
        gf.B[0] = wB + (size_t)9 * 1024 * 1024;
        gf.bias[0] = bo;
        gf.C[0] = (float*)d_out + (size_t)r0 * DIM;
        for (int i = 1; i < 9; ++i) { gf.A[i] = gf.A[0]; gf.B[i] = gf.B[0]; gf.bias[i] = gf.bias[0]; gf.C[i] = gf.C[0]; }
        gemm_bt16<true, true><<<dim3(nbm * 8), 256, 0, stream>>>(gf, nbm, 1);
    }
}

// Round 4
// 846.177 us; speedup vs baseline: 2.9762x; 1.0889x over previous
//
#include <hip/hip_runtime.h>
#include <stdint.h>
#include <stddef.h>

typedef __bf16 bf16_t;
typedef __bf16 bf16x4 __attribute__((ext_vector_type(4)));
typedef __bf16 bf16x8 __attribute__((ext_vector_type(8)));
typedef _Float16 halfx2 __attribute__((ext_vector_type(2)));
typedef float floatx4 __attribute__((ext_vector_type(4)));

#define N_ROWS 16384
#define DIM    1024

__device__ inline bf16x8 cvt_f32x8_bf16(const float* __restrict__ p) {
    floatx4 a = *(const floatx4*)p;
    floatx4 b = *(const floatx4*)(p + 4);
    bf16x8 r;
    r[0] = (bf16_t)a[0]; r[1] = (bf16_t)a[1]; r[2] = (bf16_t)a[2]; r[3] = (bf16_t)a[3];
    r[4] = (bf16_t)b[0]; r[5] = (bf16_t)b[1]; r[6] = (bf16_t)b[2]; r[7] = (bf16_t)b[3];
    return r;
}

__device__ inline void gload_lds16(const bf16_t* g, bf16_t* l) {
    __builtin_amdgcn_global_load_lds(
        (const __attribute__((address_space(1))) void*)g,
        (__attribute__((address_space(3))) void*)l,
        16, 0, 0);
}

// ---------------- f32 -> bf16 batched converter ----------------
struct CvtBatch { const float* src[10]; };

__global__ __launch_bounds__(256) void cvt_f32_bf16_kernel(CvtBatch cb, bf16_t* __restrict__ dst, size_t per) {
    const size_t i = ((size_t)blockIdx.x * 256 + threadIdx.x) * 8;
    const float* s = cb.src[blockIdx.z] + i;
    bf16_t* d = dst + (size_t)blockIdx.z * per + i;
    *(bf16x8*)d = cvt_f32x8_bf16(s);
}

struct GemmBatch {
    const bf16_t* A[9];
    const bf16_t* B[9];
    const float*  bias[9];
    void*         C[9];
};

// ---------------- 256x256 8-phase bf16 GEMM (T2+T3+T4+T5) ----------------
// C[m,n] = sum_k A[m,k]*B[n,k] + bias[n]; K=NN=1024; BK=64; 512 thr = 8 waves
// (2M x 4N); per-wave C = 128x64 (acc[8][4]). LDS 128 KiB: [dbuf2][A,B][half2]
// [128x64]. Swizzle: LDS chunk (row,col16) holds logical (row, col16^(row&7))
// -> gload_lds dest linear, source pre-swizzled, ds_read applies same XOR.
// Schedule per K-tile kt (4 phases): p0 stages (kt+1).B1; p3 stages
// (kt+2).{A0,B0,A1} after barrier#1; vmcnt(6) before p3's final barrier ->
// exactly 3 half-tiles (6 loads) in flight, everything older landed.
__global__ __launch_bounds__(512) void gemm256(GemmBatch g, int nbm) {
    // bijective XCD-stripe decode (requires nbm%8==0, grid = nbm*4*9)
    const int flat = blockIdx.x;
    const int stripe = nbm >> 3;
    const int xcd = flat & 7, slot = flat >> 3;
    const int bm = xcd * stripe + slot % stripe;
    const int rest = slot / stripe;
    const int bn = rest & 3, z = rest >> 2;

    const bf16_t* __restrict__ A = g.A[z];
    const bf16_t* __restrict__ B = g.B[z];

    __shared__ __align__(16) bf16_t lds[2][2][2][128 * 64];  // 131072 B

    const int t = threadIdx.x, lane = t & 63, w = t >> 6;
    const int wm = w >> 2, wn = w & 3;
    const int lr = lane & 15, lg = lane >> 4;
    const int sw = lr & 7;                       // row&7 for all frag rows

    floatx4 acc[8][4] = {};

    // stage one 128x64 half-tile (2 x gload_lds per thread)
    auto STAGE = [&](const bf16_t* X, int row0, int kt, int db, int mat, int h) {
#pragma unroll
        for (int i = 0; i < 2; ++i) {
            const int c = i * 512 + t;             // chunk 0..1023 (16B each)
            const int row = c >> 3, col = c & 7;
            const int cs = col ^ (row & 7);        // pre-swizzled source col
            gload_lds16(X + (size_t)(row0 + row) * 1024 + kt * 64 + cs * 8,
                        &lds[db][mat][h][i * 4096 + (w << 9)]);
        }
    };

    const int am0 = bm * 256, bn0 = bn * 256;

    // prologue: tile0 all 4 halves, tile1 {A0,B0,A1} -> vmcnt(6) = tile0 landed
    STAGE(A, am0,       0, 0, 0, 0);
    STAGE(A, am0 + 128, 0, 0, 0, 1);
    STAGE(B, bn0,       0, 0, 1, 0);
    STAGE(B, bn0 + 128, 0, 0, 1, 1);
    STAGE(A, am0,       1, 1, 0, 0);
    STAGE(B, bn0,       1, 1, 1, 0);
    STAGE(A, am0 + 128, 1, 1, 0, 1);
    __builtin_amdgcn_sched_barrier(0);
    asm volatile("s_waitcnt vmcnt(6)" ::: "memory");
    __builtin_amdgcn_sched_barrier(0);
    __builtin_amdgcn_s_barrier();
    __builtin_amdgcn_sched_barrier(0);

    auto TILE = [&](int db, int kt) {
#pragma unroll
        for (int q = 0; q < 4; ++q) {
            const int mg = (q & 1) * 4, ng = (q >> 1) * 2;
            // ds_read this phase's fragments (12 x b128)
            bf16x8 af[4][2], bfv[2][2];
#pragma unroll
            for (int mi = 0; mi < 4; ++mi)
#pragma unroll
                for (int ks = 0; ks < 2; ++ks)
                    af[mi][ks] = *(const bf16x8*)&lds[db][0][wm]
                        [((mg + mi) * 16 + lr) * 64 + ((ks * 4 + lg) ^ sw) * 8];
#pragma unroll
            for (int ni = 0; ni < 2; ++ni)
#pragma unroll
                for (int ks = 0; ks < 2; ++ks)
                    bfv[ni][ks] = *(const bf16x8*)&lds[db][1][wn >> 1]
                        [((wn & 1) * 64 + (ng + ni) * 16 + lr) * 64 + ((ks * 4 + lg) ^ sw) * 8];

            if (q == 0 && kt + 1 < 16)
                STAGE(B, bn0 + 128, kt + 1, (kt + 1) & 1, 1, 1);

            __builtin_amdgcn_sched_barrier(0);
            __builtin_amdgcn_s_barrier();          // barrier #1
            __builtin_amdgcn_sched_barrier(0);

            if (q == 3 && kt + 2 < 16) {           // into cur dbuf (all its
                STAGE(A, am0,       kt + 2, db, 0, 0);  // reads issued pre-bar)
                STAGE(B, bn0,       kt + 2, db, 1, 0);
                STAGE(A, am0 + 128, kt + 2, db, 0, 1);
            }

            __builtin_amdgcn_s_setprio(1);
#pragma unroll
            for (int mi = 0; mi < 4; ++mi)
#pragma unroll
                for (int ni = 0; ni < 2; ++ni)
#pragma unroll
                    for (int ks = 0; ks < 2; ++ks)
                        acc[mg + mi][ng + ni] = __builtin_amdgcn_mfma_f32_16x16x32_bf16(
                            af[mi][ks], bfv[ni][ks], acc[mg + mi][ng + ni], 0, 0, 0);
            __builtin_amdgcn_s_setprio(0);

            if (q == 3) {
                __builtin_amdgcn_sched_barrier(0);
                if (kt + 2 < 16) asm volatile("s_waitcnt vmcnt(6)" ::: "memory");
                else             asm volatile("s_waitcnt vmcnt(0)" ::: "memory");
            }
            __builtin_amdgcn_sched_barrier(0);
            __builtin_amdgcn_s_barrier();          // barrier #2
            __builtin_amdgcn_sched_barrier(0);
        }
    };

    for (int it = 0; it < 8; ++it) {
        TILE(0, 2 * it);
        TILE(1, 2 * it + 1);
    }

    // epilogue: C/D layout col=lane&15, row=(lane>>4)*4+rr
    const float* bias = g.bias[z];
    bf16_t* C = (bf16_t*)g.C[z];
#pragma unroll
    for (int ni = 0; ni < 4; ++ni) {
        const int gn = bn0 + wn * 64 + ni * 16 + lr;
        const float bj = bias[gn];
#pragma unroll
        for (int mi = 0; mi < 8; ++mi) {
            const int gm0 = am0 + wm * 128 + mi * 16 + lg * 4;
#pragma unroll
            for (int rr = 0; rr < 4; ++rr)
                C[(size_t)(gm0 + rr) * 1024 + gn] = (bf16_t)(acc[mi][ni][rr] + bj);
        }
    }
}

// ---------------- 128x128 2-phase GEMM (final projection only) ----------------
template<bool CF32, bool RELU>
__global__ __launch_bounds__(256) void gemm_bt16(GemmBatch g, int nbm, int nz) {
    const int K = 1024, NN = 1024;
    int bm, bn, z;
    {
        const int flat = blockIdx.x;
        if ((nbm & 7) == 0) {
            const int stripe = nbm >> 3;
            const int xcd = flat & 7;
            const int slot = flat >> 3;
            const int bml = slot % stripe;
            const int rest = slot / stripe;
            bn = rest & 7;
            z  = rest >> 3;
            bm = xcd * stripe + bml;
        } else {
            bn = flat & 7;
            const int r2 = flat >> 3;
            bm = r2 % nbm;
            z  = r2 / nbm;
        }
    }
    const int t = threadIdx.x, lane = t & 63;
    const int w = t >> 6, wm = w & 1, wn = w >> 1;

    __shared__ __align__(16) bf16_t sA[128 * 32];
    __shared__ __align__(16) bf16_t sB[128 * 32];

    const bf16_t* __restrict__ A = g.A[z];
    const bf16_t* __restrict__ B = g.B[z];

    floatx4 acc[4][4] = {};

    const int r  = t >> 2;
    const int ce = (t & 3) * 8;
    const bf16_t* gA = A + (size_t)(bm * 128 + r) * K + ce;
    const bf16_t* gB = B + (size_t)(bn * 128 + r) * K + ce;
    bf16_t* lA = &sA[(w * 64) * 8];
    bf16_t* lB = &sB[(w * 64) * 8];

    const int aoff = (lane & 15) * 32 + (lane >> 4) * 8;

    for (int kt = 0; kt < K / 32; ++kt) {
        __syncthreads();
        gload_lds16(gA,          lA);
        gload_lds16(gA + 64 * K, lA + 2048);
        gload_lds16(gB,          lB);
        gload_lds16(gB + 64 * K, lB + 2048);
        gA += 32; gB += 32;
        __syncthreads();

        bf16x8 af[4], bfr[4];
#pragma unroll
        for (int i = 0; i < 4; ++i)
            af[i] = *(const bf16x8*)&sA[(wm * 64 + i * 16) * 32 + aoff];
#pragma unroll
        for (int j = 0; j < 4; ++j)
            bfr[j] = *(const bf16x8*)&sB[(wn * 64 + j * 16) * 32 + aoff];
#pragma unroll
        for (int i = 0; i < 4; ++i)
#pragma unroll
            for (int j = 0; j < 4; ++j)
                acc[i][j] = __builtin_amdgcn_mfma_f32_16x16x32_bf16(af[i], bfr[j], acc[i][j], 0, 0, 0);
    }

    const int col = lane & 15;
    const int rbase = (lane >> 4) * 4;
    const float* bias = g.bias[z];
#pragma unroll
    for (int j = 0; j < 4; ++j) {
        const int gn = bn * 128 + wn * 64 + j * 16 + col;
        const float bj = bias[gn];
#pragma unroll
        for (int i = 0; i < 4; ++i) {
            const int gm0 = bm * 128 + wm * 64 + i * 16 + rbase;
#pragma unroll
            for (int rr = 0; rr < 4; ++rr) {
                float v = acc[i][j][rr] + bj;
                if (RELU) v = v > 0.f ? v : 0.f;
                const size_t idx = (size_t)(gm0 + rr) * NN + gn;
                if constexpr (CF32) ((float*)g.C[z])[idx] = v;
                else                ((bf16_t*)g.C[z])[idx] = (bf16_t)v;
            }
        }
    }
}

// ---------------- MFMA wave-per-row attention (barrier-free) ----------------
__global__ __launch_bounds__(256) void attn_kernel(const bf16_t* __restrict__ proj,
                                                   size_t sstride,
                                                   bf16_t* __restrict__ avg) {
    __shared__ __align__(16) bf16_t wlds[4][64 * 72];   // 36864 B
    const int t = threadIdx.x, w = t >> 6, lane = t & 63;
    const int n = blockIdx.x * 4 + w;
    const bf16_t* base = proj + (size_t)n * DIM;
    bf16_t* wb = wlds[w];

    const int q4 = lane & 15;
    const int h4 = lane >> 4;

    floatx4 oacc[4] = {};

    for (int a = 0; a < 3; ++a) {
        const bf16_t* rq = base + (size_t)(3 * a)     * sstride;
        const bf16_t* rk = base + (size_t)(3 * a + 1) * sstride;
        const bf16_t* rv = base + (size_t)(3 * a + 2) * sstride;

        bf16x8 qf[4] = {}, kf[4] = {};
        if (h4 < 2) {
            const bf16_t* qb = rq + h4 * 8 * 64 + q4;
            const bf16_t* kb = rk + h4 * 8 * 64 + q4;
#pragma unroll
            for (int i = 0; i < 4; ++i)
#pragma unroll
                for (int u = 0; u < 8; ++u) {
                    qf[i][u] = qb[u * 64 + i * 16];
                    kf[i][u] = kb[u * 64 + i * 16];
                }
        }

        floatx4 S[4][4];
#pragma unroll
        for (int dt = 0; dt < 4; ++dt)
#pragma unroll
            for (int et = 0; et < 4; ++et)
                S[dt][et] = __builtin_amdgcn_mfma_f32_16x16x32_bf16(
                    qf[dt], kf[et], (floatx4){0.f, 0.f, 0.f, 0.f}, 0, 0, 0);

#pragma unroll
        for (int et = 0; et < 4; ++et) {
            float mx = -1e30f;
#pragma unroll
            for (int dt = 0; dt < 4; ++dt)
#pragma unroll
                for (int rr = 0; rr < 4; ++rr) {
                    float v = S[dt][et][rr] * 0.125f;
                    S[dt][et][rr] = v;
                    mx = fmaxf(mx, v);
                }
            mx = fmaxf(mx, __shfl_xor(mx, 16));
            mx = fmaxf(mx, __shfl_xor(mx, 32));
            float sum = 0.f;
#pragma unroll
            for (int dt = 0; dt < 4; ++dt)
#pragma unroll
                for (int rr = 0; rr < 4; ++rr) {
                    float e = __expf(S[dt][et][rr] - mx);
                    S[dt][et][rr] = e;
                    sum += e;
                }
            sum += __shfl_xor(sum, 16);
            sum += __shfl_xor(sum, 32);
            const float inv = 1.f / sum;
#pragma unroll
            for (int dt = 0; dt < 4; ++dt)
#pragma unroll
                for (int rr = 0; rr < 4; ++rr)
                    wb[(16 * dt + h4 * 4 + rr) * 72 + 16 * et + q4] =
                        (bf16_t)(S[dt][et][rr] * inv);
        }

#pragma unroll
        for (int ks = 0; ks < 2; ++ks) {
            bf16x8 vf = *(const bf16x8*)(rv + q4 * 64 + ks * 32 + h4 * 8);
#pragma unroll
            for (int mt = 0; mt < 4; ++mt) {
                bf16x8 wf = *(const bf16x8*)&wb[(16 * mt + q4) * 72 + ks * 32 + h4 * 8];
                oacc[mt] = __builtin_amdgcn_mfma_f32_16x16x32_bf16(wf, vf, oacc[mt], 0, 0, 0);
            }
        }
    }

    bf16_t* out = avg + (size_t)n * DIM;
    const float inv3 = 1.f / 3.f;
#pragma unroll
    for (int mt = 0; mt < 4; ++mt) {
        bf16x4 pk;
#pragma unroll
        for (int rr = 0; rr < 4; ++rr) pk[rr] = (bf16_t)(oacc[mt][rr] * inv3);
        *(bf16x4*)(out + q4 * 64 + 16 * mt + h4 * 4) = pk;
    }
}

extern "C" void kernel_launch(void* const* d_in, const int* in_sizes, int n_in,
                              void* d_out, int out_size, void* d_ws, size_t ws_size,
                              hipStream_t stream) {
    const float* query = (const float*)d_in[0];
    const float* key_  = (const float*)d_in[1];
    const float* value = (const float*)d_in[2];
    const float* Wq1 = (const float*)d_in[3];  const float* bq1 = (const float*)d_in[4];
    const float* Wk1 = (const float*)d_in[5];  const float* bk1 = (const float*)d_in[6];
    const float* Wv1 = (const float*)d_in[7];  const float* bv1 = (const float*)d_in[8];
    const float* Wq2 = (const float*)d_in[9];  const float* bq2 = (const float*)d_in[10];
    const float* Wk2 = (const float*)d_in[11]; const float* bk2 = (const float*)d_in[12];
    const float* Wv2 = (const float*)d_in[13]; const float* bv2 = (const float*)d_in[14];
    const float* Wq3 = (const float*)d_in[15]; const float* bq3 = (const float*)d_in[16];
    const float* Wk3 = (const float*)d_in[17]; const float* bk3 = (const float*)d_in[18];
    const float* Wv3 = (const float*)d_in[19]; const float* bv3 = (const float*)d_in[20];
    const float* Wo  = (const float*)d_in[21]; const float* bo  = (const float*)d_in[22];

    bf16_t* wB   = (bf16_t*)d_ws;
    bf16_t* inB  = wB + (size_t)10 * 1024 * 1024;
    bf16_t* proj = inB + (size_t)3 * N_ROWS * DIM;

    const size_t fixed = ((size_t)10 * 1024 * 1024 + (size_t)3 * N_ROWS * DIM) * sizeof(bf16_t);
    size_t rem = ws_size > fixed ? ws_size - fixed : 0;
    size_t ch = rem / (10 * DIM * sizeof(bf16_t));
    if (ch > N_ROWS) ch = N_ROWS;
    // CH multiple of 2048 -> rows%256==0 and nbm%8==0 for both GEMM grids
    int CH = (int)((ch / 2048) * 2048);
    if (CH < 2048) CH = 2048;  // requires ws_size >= ~164 MB (held in all runs)
    bf16_t* avgb = proj + (size_t)9 * CH * DIM;
    const size_t sstride = (size_t)CH * DIM;

    CvtBatch cw;
    const float* worder[10] = {Wq1, Wk2, Wv1, Wq2, Wk1, Wv2, Wq3, Wk3, Wv3, Wo};
    for (int i = 0; i < 10; ++i) cw.src[i] = worder[i];
    cvt_f32_bf16_kernel<<<dim3(512, 1, 10), 256, 0, stream>>>(cw, wB, (size_t)1024 * 1024);

    CvtBatch ci;
    ci.src[0] = query; ci.src[1] = key_; ci.src[2] = value;
    for (int i = 3; i < 10; ++i) ci.src[i] = query;
    cvt_f32_bf16_kernel<<<dim3(8192, 1, 3), 256, 0, stream>>>(ci, inB, (size_t)N_ROWS * DIM);

    static const int ain[9] = {0, 2, 1, 2, 1, 0, 1, 0, 2};
    const float* bs[9] = {bq1, bk2, bv1, bq2, bk1, bv2, bq3, bk3, bv3};

    for (int r0 = 0; r0 < N_ROWS; r0 += CH) {
        const int rows = (N_ROWS - r0 < CH) ? (N_ROWS - r0) : CH;
        const int nbm256 = rows / 256;
        const int nbm128 = rows / 128;

        GemmBatch gp;
        for (int i = 0; i < 9; ++i) {
            gp.A[i]    = inB + ((size_t)ain[i] * N_ROWS + r0) * DIM;
            gp.B[i]    = wB + (size_t)i * 1024 * 1024;
            gp.bias[i] = bs[i];
            gp.C[i]    = proj + (size_t)i * sstride;
        }
        gemm256<<<dim3(nbm256 * 4 * 9), 512, 0, stream>>>(gp, nbm256);

        attn_kernel<<<dim3(rows / 4), 256, 0, stream>>>(proj, sstride, avgb);

        GemmBatch gf;
        gf.A[0] = avgb;
        gf.B[0] = wB + (size_t)9 * 1024 * 1024;
        gf.bias[0] = bo;
        gf.C[0] = (float*)d_out + (size_t)r0 * DIM;
        for (int i = 1; i < 9; ++i) { gf.A[i] = gf.A[0]; gf.B[i] = gf.B[0]; gf.bias[i] = gf.bias[0]; gf.C[i] = gf.C[0]; }
        gemm_bt16<true, true><<<dim3(nbm128 * 8), 256, 0, stream>>>(gf, nbm128, 1);
    }
}